// Round 8
// baseline (311154.370 us; speedup 1.0000x reference)
//
#include <hip/hip_runtime.h>
#include <math.h>

#define B_TOT 2048
#define T_LEN 1024
#define HID   512
#define CH    9
#define CONDK 272        // 128 + 128 + 16
#define K1X   (2*CH)     // x part of GRU1 K
#define G3    1536       // 3*HID
#define ROWS  8          // batch rows per workgroup
#define NWG   (B_TOT/ROWS)   // 256 = 1 WG per CU
#define NTHR  512
#define NB1   (HID/8)    // 64 8k-blocks, GRU1 h-part
#define NB2   (2*HID/8)  // 128 8k-blocks, GRU2

// ws layout (floats):
// Wq1: packed GRU1 h-part  [kb8][c][u][4], c = gate*2 + jhalf  (64 blocks)
// Wq2: packed GRU2         [kb8][c][u][4]                       (128 blocks)
// W1x: GRU1 x-part, R2 k-major [row][g*512+u]  (18 rows)
// Wht: W_h k-major [k][u]
#define SZ_WQ1  (NB1 * 6 * HID * 4)      // 786432
#define SZ_WQ2  (NB2 * 6 * HID * 4)      // 1572864
#define SZ_W1X  (K1X * G3)               // 27648
#define SZ_WHT  (CONDK * HID)            // 139264
#define OFF_WQ1 0
#define OFF_WQ2 (OFF_WQ1 + SZ_WQ1)
#define OFF_W1X (OFF_WQ2 + SZ_WQ2)
#define OFF_WHT (OFF_W1X + SZ_W1X)

__global__ void prep_kernel(const float* __restrict__ w_ih1, const float* __restrict__ w_hh1,
                            const float* __restrict__ w_ih2, const float* __restrict__ w_hh2,
                            const float* __restrict__ W_h, float* __restrict__ ws)
{
    int i = blockIdx.x * blockDim.x + threadIdx.x;
    const int total = SZ_WQ1 + SZ_WQ2 + SZ_W1X + SZ_WHT;
    if (i >= total) return;
    if (i < SZ_WQ1 + SZ_WQ2) {
        int base = (i < SZ_WQ1) ? 0 : SZ_WQ1;
        int idx = i - base;
        int j   = idx & 3;
        int f   = idx >> 2;
        int u   = f & (HID-1);
        int r   = f >> 9;            // /512
        int c   = r % 6;
        int kb8 = r / 6;
        int g   = c >> 1, jh = c & 1;
        int k   = kb8*8 + jh*4 + j;
        float v;
        if (i < SZ_WQ1) v = w_hh1[(size_t)(g*HID + u)*HID + k];
        else            v = (k < HID) ? w_hh2[(size_t)(g*HID + u)*HID + k]
                                      : w_ih2[(size_t)(g*HID + u)*HID + (k - HID)];
        ws[i] = v;
    } else if (i < SZ_WQ1 + SZ_WQ2 + SZ_W1X) {
        int j = i - (SZ_WQ1 + SZ_WQ2);
        int row = j / G3, col = j % G3;
        ws[i] = w_ih1[(size_t)col*K1X + row];
    } else {
        int j = i - (SZ_WQ1 + SZ_WQ2 + SZ_W1X);
        int k = j / HID, u = j % HID;
        ws[i] = W_h[(size_t)u*CONDK + k];
    }
}

__device__ __forceinline__ float sigmf(float x) { return 1.0f / (1.0f + expf(-x)); }

#define F4E(v, j) ((j)==0 ? (v).x : ((j)==1 ? (v).y : ((j)==2 ? (v).z : (v).w)))

// load one 8k block (6 float4) into BUF
#define LB(P4, KB, BUF)                                                     \
    { _Pragma("unroll")                                                     \
      for (int c_ = 0; c_ < 6; ++c_)                                        \
          BUF[c_] = (P4)[((size_t)(KB)*6 + c_)*HID + tid]; }

// compute one 8k block; KL = block index into HS (0..63); A2 = third-gate acc
#define CB(HS, A2, KL, BUF)                                                 \
    { _Pragma("unroll")                                                     \
      for (int jh_ = 0; jh_ < 2; ++jh_) {                                   \
        _Pragma("unroll")                                                   \
        for (int j_ = 0; j_ < 4; ++j_) {                                    \
            int k_ = (KL)*8 + jh_*4 + j_;                                   \
            float w_r = F4E(BUF[jh_],   j_);                                \
            float w_z = F4E(BUF[2+jh_], j_);                                \
            float w_n = F4E(BUF[4+jh_], j_);                                \
            float4 a0 = *(const float4*)&HS[k_][0];                         \
            float4 a1 = *(const float4*)&HS[k_][4];                         \
            ar[0]=fmaf(a0.x,w_r,ar[0]); az[0]=fmaf(a0.x,w_z,az[0]); A2[0]=fmaf(a0.x,w_n,A2[0]); \
            ar[1]=fmaf(a0.y,w_r,ar[1]); az[1]=fmaf(a0.y,w_z,az[1]); A2[1]=fmaf(a0.y,w_n,A2[1]); \
            ar[2]=fmaf(a0.z,w_r,ar[2]); az[2]=fmaf(a0.z,w_z,az[2]); A2[2]=fmaf(a0.z,w_n,A2[2]); \
            ar[3]=fmaf(a0.w,w_r,ar[3]); az[3]=fmaf(a0.w,w_z,az[3]); A2[3]=fmaf(a0.w,w_n,A2[3]); \
            ar[4]=fmaf(a1.x,w_r,ar[4]); az[4]=fmaf(a1.x,w_z,az[4]); A2[4]=fmaf(a1.x,w_n,A2[4]); \
            ar[5]=fmaf(a1.y,w_r,ar[5]); az[5]=fmaf(a1.y,w_z,az[5]); A2[5]=fmaf(a1.y,w_n,A2[5]); \
            ar[6]=fmaf(a1.z,w_r,ar[6]); az[6]=fmaf(a1.z,w_z,az[6]); A2[6]=fmaf(a1.z,w_n,A2[6]); \
            ar[7]=fmaf(a1.w,w_r,ar[7]); az[7]=fmaf(a1.w,w_z,az[7]); A2[7]=fmaf(a1.w,w_n,A2[7]); \
        } } }

__global__ __launch_bounds__(NTHR, 2)
void note_decoder_kernel(const float* __restrict__ z, const float* __restrict__ se,
                         const float* __restrict__ skel, const float* __restrict__ cond,
                         const float* __restrict__ rnd,
                         const float* __restrict__ b_h,
                         const float* __restrict__ b_ih1, const float* __restrict__ b_hh1,
                         const float* __restrict__ b_ih2, const float* __restrict__ b_hh2,
                         const float* __restrict__ W_out, const float* __restrict__ b_out,
                         const float* __restrict__ ws,
                         float* __restrict__ out)
{
    __shared__ float h1s[HID][ROWS];
    __shared__ float h2s[HID][ROWS];
    __shared__ float xf[2*CH][ROWS];      // x = [out(9) | skel(9)], k-major
    __shared__ float wouts[HID][CH];

    const float4* __restrict__ Wq1 = (const float4*)(ws + OFF_WQ1);
    const float4* __restrict__ Wq2 = (const float4*)(ws + OFF_WQ2);
    const float*  __restrict__ W1x = ws + OFF_W1X;
    const float*  __restrict__ Wht = ws + OFF_WHT;

    const int tid  = threadIdx.x;          // owns hidden unit `tid`
    const int row0 = blockIdx.x * ROWS;

    // stage W_out as [u][c]
    for (int i = tid; i < CH*HID; i += NTHR) {
        int c = i / HID, u = i % HID;
        wouts[u][c] = W_out[i];
    }
    // stage zc = [z | skel_encoded | cond] into h2s scratch, k-major
    for (int i = tid; i < ROWS*CONDK; i += NTHR) {
        int b = i / CONDK, k = i % CONDK;
        float v;
        if (k < 128)       v = z[(row0 + b)*128 + k];
        else if (k < 256)  v = se[(row0 + b)*128 + (k - 128)];
        else               v = cond[(row0 + b)*16 + (k - 256)];
        h2s[k][b] = v;
    }
    if (tid < ROWS*CH) xf[tid % CH][tid / CH] = 0.0f;   // out0 = 0 (xf[c][b])
    __syncthreads();

    // h1_0 = tanh(zc @ W_h^T + b_h)  (sequential k per (u,b): R2 order)
    {
        float acc[ROWS];
        #pragma unroll
        for (int b = 0; b < ROWS; ++b) acc[b] = 0.0f;
        for (int k = 0; k < CONDK; ++k) {
            float w = Wht[k*HID + tid];
            float4 a0 = *(const float4*)&h2s[k][0];
            float4 a1 = *(const float4*)&h2s[k][4];
            float hv[ROWS] = {a0.x,a0.y,a0.z,a0.w,a1.x,a1.y,a1.z,a1.w};
            #pragma unroll
            for (int b = 0; b < ROWS; ++b) acc[b] = fmaf(hv[b], w, acc[b]);
        }
        float bh = b_h[tid];
        __syncthreads();   // done reading zc scratch
        #pragma unroll
        for (int b = 0; b < ROWS; ++b) acc[b] = tanhf(acc[b] + bh);
        *(float4*)&h1s[tid][0] = make_float4(acc[0],acc[1],acc[2],acc[3]);
        *(float4*)&h1s[tid][4] = make_float4(acc[4],acc[5],acc[6],acc[7]);
    }
    __syncthreads();

    // hoisted biases
    const float br1 = b_ih1[tid]         + b_hh1[tid];
    const float bz1 = b_ih1[HID + tid]   + b_hh1[HID + tid];
    const float bi1 = b_ih1[2*HID + tid];
    const float bn1 = b_hh1[2*HID + tid];
    const float br2 = b_ih2[tid]         + b_hh2[tid];
    const float bz2 = b_ih2[HID + tid]   + b_hh2[HID + tid];
    const float bi2 = b_ih2[2*HID + tid];
    const float bn2 = b_hh2[2*HID + tid];

    const int wv = tid >> 6, ln = tid & 63;

    float4 bufA[6], bufB[6];

    for (int t = 0; t < T_LEN; ++t) {
        // stage skel half of x; feedback xf[0..8] from prev step
        if (tid < ROWS*CH) {
            int b = tid / CH, c = tid % CH;
            xf[CH + c][b] = skel[((size_t)(row0 + b)*T_LEN + t)*CH + c];
        }
        __syncthreads();                                   // A

        // ---- GRU1 h-part: 64 blocks, register ping-pong (float4 weight loads) ----
        float ar[ROWS], az[ROWS], ai[ROWS], ah[ROWS];
        #pragma unroll
        for (int b = 0; b < ROWS; ++b) { ar[b]=0.f; az[b]=0.f; ai[b]=0.f; ah[b]=0.f; }
        LB(Wq1, 0, bufA);
        LB(Wq1, 1, bufB);
        for (int i = 0; i + 3 < NB1; i += 2) {
            CB(h1s, ah, i,   bufA); LB(Wq1, i+2, bufA);
            CB(h1s, ah, i+1, bufB); LB(Wq1, i+3, bufB);
        }
        CB(h1s, ah, NB1-2, bufA);
        CB(h1s, ah, NB1-1, bufB);
        // x-part: 18 rows, scalar streaming (R2-exact)
        #pragma unroll
        for (int k = 0; k < K1X; ++k) {
            const float* wr = W1x + (size_t)k*G3;
            float w_r = wr[tid], w_z = wr[HID + tid], w_n = wr[2*HID + tid];
            float4 a  = *(const float4*)&xf[k][0];
            float4 a1 = *(const float4*)&xf[k][4];
            ar[0]=fmaf(a.x,w_r,ar[0]);  az[0]=fmaf(a.x,w_z,az[0]);  ai[0]=fmaf(a.x,w_n,ai[0]);
            ar[1]=fmaf(a.y,w_r,ar[1]);  az[1]=fmaf(a.y,w_z,az[1]);  ai[1]=fmaf(a.y,w_n,ai[1]);
            ar[2]=fmaf(a.z,w_r,ar[2]);  az[2]=fmaf(a.z,w_z,az[2]);  ai[2]=fmaf(a.z,w_n,ai[2]);
            ar[3]=fmaf(a.w,w_r,ar[3]);  az[3]=fmaf(a.w,w_z,az[3]);  ai[3]=fmaf(a.w,w_n,ai[3]);
            ar[4]=fmaf(a1.x,w_r,ar[4]); az[4]=fmaf(a1.x,w_z,az[4]); ai[4]=fmaf(a1.x,w_n,ai[4]);
            ar[5]=fmaf(a1.y,w_r,ar[5]); az[5]=fmaf(a1.y,w_z,az[5]); ai[5]=fmaf(a1.y,w_n,ai[5]);
            ar[6]=fmaf(a1.z,w_r,ar[6]); az[6]=fmaf(a1.z,w_z,az[6]); ai[6]=fmaf(a1.z,w_n,ai[6]);
            ar[7]=fmaf(a1.w,w_r,ar[7]); az[7]=fmaf(a1.w,w_z,az[7]); ai[7]=fmaf(a1.w,w_n,ai[7]);
        }
        float4 p0 = *(const float4*)&h1s[tid][0];
        float4 p1 = *(const float4*)&h1s[tid][4];
        float h1old[ROWS] = {p0.x,p0.y,p0.z,p0.w,p1.x,p1.y,p1.z,p1.w};
        float h1n[ROWS];
        #pragma unroll
        for (int b = 0; b < ROWS; ++b) {
            float r  = sigmf(ar[b] + br1);
            float zg = sigmf(az[b] + bz1);
            float n  = tanhf(fmaf(r, ah[b] + bn1, ai[b] + bi1));
            h1n[b] = (1.0f - zg)*n + zg*h1old[b];
        }
        __syncthreads();                                   // B: h1 reads done
        *(float4*)&h1s[tid][0] = make_float4(h1n[0],h1n[1],h1n[2],h1n[3]);
        *(float4*)&h1s[tid][4] = make_float4(h1n[4],h1n[5],h1n[6],h1n[7]);
        if (t == 0) {      // hx[1] = hx[0] at i==0
            *(float4*)&h2s[tid][0] = make_float4(h1n[0],h1n[1],h1n[2],h1n[3]);
            *(float4*)&h2s[tid][4] = make_float4(h1n[4],h1n[5],h1n[6],h1n[7]);
        }
        __syncthreads();                                   // C

        // ---- GRU2: 128 blocks (0..63 h2-part -> ah, 64..127 h1-part -> ai) ----
        #pragma unroll
        for (int b = 0; b < ROWS; ++b) { ar[b]=0.f; az[b]=0.f; ai[b]=0.f; ah[b]=0.f; }
        LB(Wq2, 0, bufA);
        LB(Wq2, 1, bufB);
        for (int i = 0; i + 3 < NB2/2; i += 2) {
            CB(h2s, ah, i,   bufA); LB(Wq2, i+2, bufA);
            CB(h2s, ah, i+1, bufB); LB(Wq2, i+3, bufB);
        }
        CB(h2s, ah, NB2/2-2, bufA); LB(Wq2, NB2/2,   bufA);
        CB(h2s, ah, NB2/2-1, bufB); LB(Wq2, NB2/2+1, bufB);
        for (int i = NB2/2; i + 3 < NB2; i += 2) {
            CB(h1s, ai, i   - NB2/2, bufA); LB(Wq2, i+2, bufA);
            CB(h1s, ai, i+1 - NB2/2, bufB); LB(Wq2, i+3, bufB);
        }
        CB(h1s, ai, NB2/2-2, bufA);
        CB(h1s, ai, NB2/2-1, bufB);
        float4 q0 = *(const float4*)&h2s[tid][0];
        float4 q1 = *(const float4*)&h2s[tid][4];
        float h2old[ROWS] = {q0.x,q0.y,q0.z,q0.w,q1.x,q1.y,q1.z,q1.w};
        float h2n[ROWS];
        #pragma unroll
        for (int b = 0; b < ROWS; ++b) {
            float r  = sigmf(ar[b] + br2);
            float zg = sigmf(az[b] + bz2);
            float n  = tanhf(fmaf(r, ah[b] + bn2, ai[b] + bi2));
            h2n[b] = (1.0f - zg)*n + zg*h2old[b];
        }
        __syncthreads();                                   // D
        *(float4*)&h2s[tid][0] = make_float4(h2n[0],h2n[1],h2n[2],h2n[3]);
        *(float4*)&h2s[tid][4] = make_float4(h2n[4],h2n[5],h2n[6],h2n[7]);
        __syncthreads();                                   // E

        // ---- note = tanh(h2) @ W_out^T + b_out; Bernoulli sample (R2-exact) ----
        {
            float na[CH];
            #pragma unroll
            for (int c = 0; c < CH; ++c) na[c] = 0.0f;
            for (int kk = ln; kk < HID; kk += 64) {
                float th = tanhf(h2s[kk][wv]);
                #pragma unroll
                for (int c = 0; c < CH; ++c) na[c] = fmaf(th, wouts[kk][c], na[c]);
            }
            #pragma unroll
            for (int c = 0; c < CH; ++c) {
                #pragma unroll
                for (int off = 32; off; off >>= 1)
                    na[c] += __shfl_xor(na[c], off, 64);
            }
            if (ln < CH) {
                int c = ln;
                float note = na[c] + b_out[c];
                float sg = sigmf(note);
                float rv = rnd[((size_t)t*B_TOT + row0 + wv)*CH + c];
                xf[c][wv] = (sg - rv > 0.0f) ? 1.0f : 0.0f;   // feedback bit
                out[((size_t)(row0 + wv)*T_LEN + t)*CH + c] = note;
            }
        }
        __syncthreads();                                   // F
    }
}

extern "C" void kernel_launch(void* const* d_in, const int* in_sizes, int n_in,
                              void* d_out, int out_size, void* d_ws, size_t ws_size,
                              hipStream_t stream)
{
    const float* z     = (const float*)d_in[0];
    const float* se    = (const float*)d_in[1];
    const float* skel  = (const float*)d_in[2];
    const float* cond  = (const float*)d_in[3];
    const float* rnd   = (const float*)d_in[4];
    const float* W_h   = (const float*)d_in[5];
    const float* b_h   = (const float*)d_in[6];
    const float* w_ih1 = (const float*)d_in[7];
    const float* w_hh1 = (const float*)d_in[8];
    const float* b_ih1 = (const float*)d_in[9];
    const float* b_hh1 = (const float*)d_in[10];
    const float* w_ih2 = (const float*)d_in[11];
    const float* w_hh2 = (const float*)d_in[12];
    const float* b_ih2 = (const float*)d_in[13];
    const float* b_hh2 = (const float*)d_in[14];
    const float* W_out = (const float*)d_in[15];
    const float* b_out = (const float*)d_in[16];
    float* ws  = (float*)d_ws;
    float* out = (float*)d_out;

    const int total = SZ_WQ1 + SZ_WQ2 + SZ_W1X + SZ_WHT;
    prep_kernel<<<(total + 255)/256, 256, 0, stream>>>(w_ih1, w_hh1, w_ih2, w_hh2, W_h, ws);
    note_decoder_kernel<<<NWG, NTHR, 0, stream>>>(z, se, skel, cond, rnd, b_h,
                                                  b_ih1, b_hh1, b_ih2, b_hh2,
                                                  W_out, b_out, ws, out);
}